// Round 1
// baseline (307.324 us; speedup 1.0000x reference)
//
#include <hip/hip_runtime.h>
#include <hip/hip_bf16.h>

// Problem constants (from reference)
#define B_   4
#define S_   2048
#define DIN  1024
#define DH   1024
#define DOUT 1024

typedef __attribute__((ext_vector_type(8))) __bf16 bf16x8;
typedef __attribute__((ext_vector_type(4))) float floatx4;
typedef unsigned short u16;
typedef unsigned int u32;

__device__ inline u16 f2bf(float f) {
  union { float f; u32 u; } x; x.f = f;
  u32 r = x.u + 0x7fffu + ((x.u >> 16) & 1u);  // RTNE
  return (u16)(r >> 16);
}

// ---------------------------------------------------------------------------
// fp32 -> bf16 cast, vectorized (float4 in, ushort4 out)
// ---------------------------------------------------------------------------
__global__ __launch_bounds__(256)
void cast_f32_bf16(const float* __restrict__ in, u16* __restrict__ out, long n4) {
  long i = (long)blockIdx.x * 256 + threadIdx.x;
  if (i >= n4) return;
  float4 v = ((const float4*)in)[i];
  ushort4 o;
  o.x = f2bf(v.x); o.y = f2bf(v.y); o.z = f2bf(v.z); o.w = f2bf(v.w);
  ((ushort4*)out)[i] = o;
}

// ---------------------------------------------------------------------------
// bf16 32x32-tile transpose (for V -> V^T so PV becomes a B^T GEMM)
// in: [S_][DH] per batch, out: [DH][S_] per batch
// ---------------------------------------------------------------------------
__global__ __launch_bounds__(256)
void transpose_bf16(const u16* __restrict__ in, u16* __restrict__ out) {
  __shared__ u16 t[32][33];
  const int b = blockIdx.z;
  const int r0 = blockIdx.y * 32, c0 = blockIdx.x * 32;
  const int tx = threadIdx.x & 31, ty = threadIdx.x >> 5;  // 32 x 8
  const u16* ib = in + (long)b * S_ * DH;
  u16* ob = out + (long)b * DH * S_;
#pragma unroll
  for (int i = 0; i < 4; ++i) {
    int r = ty + i * 8;
    t[r][tx] = ib[(long)(r0 + r) * DH + (c0 + tx)];
  }
  __syncthreads();
#pragma unroll
  for (int i = 0; i < 4; ++i) {
    int r = ty + i * 8;
    ob[(long)(c0 + r) * S_ + (r0 + tx)] = t[tx][r];
  }
}

// ---------------------------------------------------------------------------
// Row softmax: one block per row of E [B*S_ rows][S_ fp32] -> bf16 A
// ---------------------------------------------------------------------------
__global__ __launch_bounds__(256)
void softmax_row(const float* __restrict__ E, u16* __restrict__ A) {
  const long row = blockIdx.x;
  const float* e = E + row * (long)S_;
  u16* a = A + row * (long)S_;
  const int tid = threadIdx.x;
  const int w = tid >> 6, l = tid & 63;
  __shared__ float sred[8];

  float4 v0 = ((const float4*)e)[tid * 2];
  float4 v1 = ((const float4*)e)[tid * 2 + 1];
  float p[8] = {v0.x, v0.y, v0.z, v0.w, v1.x, v1.y, v1.z, v1.w};

  float mx = p[0];
#pragma unroll
  for (int j = 1; j < 8; ++j) mx = fmaxf(mx, p[j]);
#pragma unroll
  for (int o = 32; o > 0; o >>= 1) mx = fmaxf(mx, __shfl_xor(mx, o));
  if (l == 0) sred[w] = mx;
  __syncthreads();
  mx = fmaxf(fmaxf(sred[0], sred[1]), fmaxf(sred[2], sred[3]));

  float sum = 0.f;
#pragma unroll
  for (int j = 0; j < 8; ++j) { p[j] = __expf(p[j] - mx); sum += p[j]; }
#pragma unroll
  for (int o = 32; o > 0; o >>= 1) sum += __shfl_xor(sum, o);
  if (l == 0) sred[4 + w] = sum;
  __syncthreads();
  sum = sred[4] + sred[5] + sred[6] + sred[7];
  const float inv = 1.0f / sum;

  ushort4 o0, o1;
  o0.x = f2bf(p[0] * inv); o0.y = f2bf(p[1] * inv);
  o0.z = f2bf(p[2] * inv); o0.w = f2bf(p[3] * inv);
  o1.x = f2bf(p[4] * inv); o1.y = f2bf(p[5] * inv);
  o1.z = f2bf(p[6] * inv); o1.w = f2bf(p[7] * inv);
  ((ushort4*)a)[tid * 2]     = o0;
  ((ushort4*)a)[tid * 2 + 1] = o1;
}

// ---------------------------------------------------------------------------
// bf16 B^T GEMM:  C[M,N] = A[M,K] @ B[N,K]^T  (+ epilogue)
// 128x128 tile, BK=32, 256 threads (4 waves, 2x2), 16x16x32 MFMA,
// global_load_lds width=16 staging (linear LDS, no swizzle this round).
// lda = ldb = K, ldc = N, mask ld = N. Batched via blockIdx.z + strides.
// ---------------------------------------------------------------------------
#define EPI_BF16_BIAS 0
#define EPI_F32_MASK  1
#define EPI_BF16      2
#define EPI_F32_BIAS  3

template <int EPI>
__global__ __launch_bounds__(256, 2)
void gemm_bt(const u16* __restrict__ A, const u16* __restrict__ Bm,
             void* __restrict__ C, const float* __restrict__ bias,
             const int* __restrict__ mask,
             int M, int N, int K, float scale,
             long sA, long sB, long sC, long sMask) {
  __shared__ u16 lA[128 * 32];
  __shared__ u16 lB[128 * 32];

  const int tid = threadIdx.x;
  const int w = tid >> 6;
  const int l = tid & 63;
  const int wr = w >> 1, wc = w & 1;           // wave 2x2 grid over tile
  const int lr = l & 15;
  const int ko = (l >> 4) << 3;                // k-offset of this lane's frag

  const int bz = blockIdx.z;
  const long arow0 = (long)blockIdx.y * 128;
  const long bcol0 = (long)blockIdx.x * 128;

  const u16* Abase = A + bz * sA + arow0 * K;
  const u16* Bbase = Bm + bz * sB + bcol0 * K;

  floatx4 acc[4][4] = {};

  for (int k0 = 0; k0 < K; k0 += 32) {
    // Stage A,B tiles: 128x32 bf16 = 512 chunks of 16B; 2 issues x 256 thr.
#pragma unroll
    for (int i = 0; i < 2; ++i) {
      const int chunk = i * 256 + tid;
      const int row = chunk >> 2;
      const int cko = (chunk & 3) << 3;
      const int ldsbase = (i * 256 + w * 64) * 8;  // wave-uniform, in u16
      __builtin_amdgcn_global_load_lds(
          (const __attribute__((address_space(1))) u32*)(Abase + (long)row * K + k0 + cko),
          (__attribute__((address_space(3))) u32*)(&lA[ldsbase]), 16, 0, 0);
      __builtin_amdgcn_global_load_lds(
          (const __attribute__((address_space(1))) u32*)(Bbase + (long)row * K + k0 + cko),
          (__attribute__((address_space(3))) u32*)(&lB[ldsbase]), 16, 0, 0);
    }
    __syncthreads();

    bf16x8 af[4], bfv[4];
#pragma unroll
    for (int m = 0; m < 4; ++m)
      af[m] = *(const bf16x8*)&lA[(wr * 64 + m * 16 + lr) * 32 + ko];
#pragma unroll
    for (int n = 0; n < 4; ++n)
      bfv[n] = *(const bf16x8*)&lB[(wc * 64 + n * 16 + lr) * 32 + ko];
#pragma unroll
    for (int m = 0; m < 4; ++m)
#pragma unroll
      for (int n = 0; n < 4; ++n)
        acc[m][n] = __builtin_amdgcn_mfma_f32_16x16x32_bf16(af[m], bfv[n], acc[m][n], 0, 0, 0);
    __syncthreads();
  }

  // Epilogue. C/D layout: col = l&15, row = (l>>4)*4 + r  [m89-verified]
  const int r4 = (l >> 4) << 2;
#pragma unroll
  for (int m = 0; m < 4; ++m) {
#pragma unroll
    for (int n = 0; n < 4; ++n) {
#pragma unroll
      for (int r = 0; r < 4; ++r) {
        const long row = arow0 + wr * 64 + m * 16 + r4 + r;
        const long col = bcol0 + wc * 64 + n * 16 + lr;
        float v = acc[m][n][r];
        if constexpr (EPI == EPI_BF16_BIAS) {
          v += bias[col];
          ((u16*)C)[bz * sC + row * N + col] = f2bf(v);
        } else if constexpr (EPI == EPI_BF16) {
          ((u16*)C)[bz * sC + row * N + col] = f2bf(v);
        } else if constexpr (EPI == EPI_F32_BIAS) {
          v += bias[col];
          ((float*)C)[bz * sC + row * N + col] = v;
        } else {  // EPI_F32_MASK: e = mask ? v*scale : -2^15
          v *= scale;
          const int mk = mask[bz * sMask + row * (long)N + col];
          ((float*)C)[bz * sC + row * N + col] = (mk == 0) ? -32768.0f : v;
        }
      }
    }
  }
}

// ---------------------------------------------------------------------------
extern "C" void kernel_launch(void* const* d_in, const int* in_sizes, int n_in,
                              void* d_out, int out_size, void* d_ws, size_t ws_size,
                              hipStream_t stream) {
  const float* q    = (const float*)d_in[0];
  const float* k    = (const float*)d_in[1];
  const float* v    = (const float*)d_in[2];
  const int*   mask = (const int*)d_in[3];
  const float* Wq   = (const float*)d_in[4];
  const float* bq   = (const float*)d_in[5];
  const float* Wk   = (const float*)d_in[6];
  const float* bk   = (const float*)d_in[7];
  const float* Wv   = (const float*)d_in[8];
  const float* bv   = (const float*)d_in[9];
  const float* Wo   = (const float*)d_in[10];
  const float* bo   = (const float*)d_in[11];

  const long BS = (long)B_ * S_;      // 8192
  const long nQ = BS * DH;            // 8,388,608
  const long nW = (long)DH * DIN;     // 1,048,576
  const long nE = (long)B_ * S_ * S_; // 16,777,216

  char* ws = (char*)d_ws;
  size_t off = 0;
  auto alloc = [&](size_t bytes) {
    void* p = ws + off; off += (bytes + 255) & ~(size_t)255; return p;
  };

  u16* qb  = (u16*)alloc(nQ * 2);
  u16* kb  = (u16*)alloc(nQ * 2);
  u16* vb  = (u16*)alloc(nQ * 2);
  u16* wqb = (u16*)alloc(nW * 2);
  u16* wkb = (u16*)alloc(nW * 2);
  u16* wvb = (u16*)alloc(nW * 2);
  u16* wob = (u16*)alloc(nW * 2);
  u16* Qb  = (u16*)alloc(nQ * 2);
  u16* Kb  = (u16*)alloc(nQ * 2);
  u16* Vb  = (u16*)alloc(nQ * 2);
  u16* VT  = (u16*)alloc(nQ * 2);
  float* E = (float*)alloc(nE * 4);
  // Aliases over consumed buffers (safe: written strictly after last read):
  u16* Apb = qb;  // softmax probs, 33.55 MB over qb+kb
  u16* Yb  = vb;  // attention output, 16.78 MB over vb

  // 1. casts
  auto cast = [&](const float* src, u16* dst, long n) {
    long n4 = n / 4;
    cast_f32_bf16<<<dim3((unsigned)((n4 + 255) / 256)), 256, 0, stream>>>(src, dst, n4);
  };
  cast(q, qb, nQ); cast(k, kb, nQ); cast(v, vb, nQ);
  cast(Wq, wqb, nW); cast(Wk, wkb, nW); cast(Wv, wvb, nW); cast(Wo, wob, nW);

  // 2. QKV projections: X @ W^T + b  (M=8192, N=1024, K=1024)
  {
    dim3 g(DH / 128, BS / 128, 1);
    gemm_bt<EPI_BF16_BIAS><<<g, 256, 0, stream>>>(qb, wqb, Qb, bq, nullptr,
        (int)BS, DH, DIN, 1.f, 0, 0, 0, 0);
    gemm_bt<EPI_BF16_BIAS><<<g, 256, 0, stream>>>(kb, wkb, Kb, bk, nullptr,
        (int)BS, DH, DIN, 1.f, 0, 0, 0, 0);
    gemm_bt<EPI_BF16_BIAS><<<g, 256, 0, stream>>>(vb, wvb, Vb, bv, nullptr,
        (int)BS, DH, DIN, 1.f, 0, 0, 0, 0);
  }

  // 3. V -> V^T per batch
  {
    dim3 g(DH / 32, S_ / 32, B_);
    transpose_bf16<<<g, 256, 0, stream>>>(Vb, VT);
  }

  // 4. E = (Q @ K^T) / 32, mask-filled with -2^15  (batched, M=N=2048, K=1024)
  {
    dim3 g(S_ / 128, S_ / 128, B_);
    gemm_bt<EPI_F32_MASK><<<g, 256, 0, stream>>>(Qb, Kb, (void*)E, nullptr, mask,
        S_, S_, DH, 0.03125f,
        (long)S_ * DH, (long)S_ * DH, (long)S_ * S_, (long)S_ * S_);
  }

  // 5. row softmax -> bf16 probs
  softmax_row<<<dim3((unsigned)(B_ * S_)), 256, 0, stream>>>(E, Apb);

  // 6. Y = A @ V  ==  A[M=S,K=S] @ VT[N=DH,K=S]^T  (batched)
  {
    dim3 g(DH / 128, S_ / 128, B_);
    gemm_bt<EPI_BF16><<<g, 256, 0, stream>>>(Apb, VT, Yb, nullptr, nullptr,
        S_, DH, S_, 1.f,
        (long)S_ * S_, (long)DH * S_, (long)S_ * DH, 0);
  }

  // 7. out = Y @ Wo^T + bo  (M=8192, N=1024, K=1024) -> fp32 d_out
  {
    dim3 g(DOUT / 128, BS / 128, 1);
    gemm_bt<EPI_F32_BIAS><<<g, 256, 0, stream>>>(Yb, wob, d_out, bo, nullptr,
        (int)BS, DOUT, DH, 1.f, 0, 0, 0, 0);
  }
}